// Round 1
// baseline (84.885 us; speedup 1.0000x reference)
//
#include <hip/hip_runtime.h>
#include <cstdint>

// OctantQuery: pcs [B,3,N] f32 -> out [B,N,9,K] int32 (JAX x64 off => int32).
// One wave (64 lanes) per center point. Lanes scan 64 candidate j's per
// iteration; per-octant __ballot + mbcnt prefix reproduces the reference's
// sequential (ascending-j) fill order exactly. Counts live in SGPRs
// (wave-uniform after ballot). All 9*K slots are written every launch.

#define NPTS   2048
#define KSAMP  32
#define RAD2   0.16f

__device__ __forceinline__ unsigned rank_below(unsigned long long mask) {
    // number of set bits in `mask` at lane positions strictly below mine
    return __builtin_amdgcn_mbcnt_hi((unsigned)(mask >> 32),
           __builtin_amdgcn_mbcnt_lo((unsigned)(mask & 0xffffffffu), 0u));
}

__global__ __launch_bounds__(256) void octant_query_kernel(
    const float* __restrict__ pcs, int* __restrict__ out, int nwaves) {
#pragma clang fp contract(off)
    const int wave = (int)((blockIdx.x * blockDim.x + threadIdx.x) >> 6);
    const int lane = (int)(threadIdx.x & 63);
    if (wave >= nwaves) return;
    const int b = wave >> 11;        // N = 2048
    const int i = wave & (NPTS - 1);

    const float* __restrict__ px = pcs + (size_t)b * 3 * NPTS;
    const float* __restrict__ py = px + NPTS;
    const float* __restrict__ pz = py + NPTS;

    const float cx = px[i];
    const float cy = py[i];
    const float cz = pz[i];

    int* __restrict__ obase = out + (size_t)(b * NPTS + i) * 9 * KSAMP;

    int cnt0 = 0, cnt1 = 0, cnt2 = 0, cnt3 = 0;
    int cnt4 = 0, cnt5 = 0, cnt6 = 0, cnt7 = 0;

    for (int c = 0; c < NPTS; c += 64) {
        const int j = c + lane;
        const float dx = px[j] - cx;
        const float dy = py[j] - cy;
        const float dz = pz[j] - cz;
        // match numpy rounding: no fp contraction (pragma above), left-assoc
        float d2 = dx * dx;
        d2 = d2 + dy * dy;
        d2 = d2 + dz * dz;
        const bool within = (d2 < RAD2) && (j != i);
        const int code = (dx > 0.f ? 1 : 0) + (dy > 0.f ? 2 : 0)
                       + (dz > 0.f ? 4 : 0);

#define DO_OCT(o, cnt)                                                      \
        {                                                                   \
            const bool m = within && (code == (o));                         \
            const unsigned long long mask = __ballot(m);                    \
            if (m) {                                                        \
                const int r = cnt + (int)rank_below(mask);                  \
                if (r < KSAMP) obase[(o) * KSAMP + r] = j;                  \
            }                                                               \
            cnt += (int)__popcll(mask);                                     \
        }
        DO_OCT(0, cnt0) DO_OCT(1, cnt1) DO_OCT(2, cnt2) DO_OCT(3, cnt3)
        DO_OCT(4, cnt4) DO_OCT(5, cnt5) DO_OCT(6, cnt6) DO_OCT(7, cnt7)
#undef DO_OCT
    }

    // pad remaining slots with center index i (each slot written exactly once)
#define FILL(o, cnt)                                                        \
        {                                                                   \
            const int s = cnt + lane;                                       \
            if (s < KSAMP) obase[(o) * KSAMP + s] = i;                      \
        }
    FILL(0, cnt0) FILL(1, cnt1) FILL(2, cnt2) FILL(3, cnt3)
    FILL(4, cnt4) FILL(5, cnt5) FILL(6, cnt6) FILL(7, cnt7)
#undef FILL
    if (lane < KSAMP) obase[8 * KSAMP + lane] = i;
}

extern "C" void kernel_launch(void* const* d_in, const int* in_sizes, int n_in,
                              void* d_out, int out_size, void* d_ws, size_t ws_size,
                              hipStream_t stream) {
    const float* pcs = (const float*)d_in[0];
    int* out = (int*)d_out;
    const int B = in_sizes[0] / (3 * NPTS);   // 4
    const int nwaves = B * NPTS;              // one wave per center
    const int block = 256;                    // 4 waves/block
    const int grid = (nwaves * 64 + block - 1) / block;
    octant_query_kernel<<<grid, block, 0, stream>>>(pcs, out, nwaves);
}

// Round 2
// 70.607 us; speedup vs baseline: 1.2022x; 1.2022x over previous
//
#include <hip/hip_runtime.h>
#include <cstdint>

// OctantQuery: pcs [B,3,N] f32 -> out [B,N,9,K] int32.
// One wave (64 lanes) per center point. Lanes scan 64 candidate j's per
// iteration. Sparse-aware: ~0.6% of pairs are within radius, so ~70% of
// 64-candidate chunks are empty -> ballot(within) once and skip the whole
// octant pipeline on a wave-uniform branch. Nonempty chunks build per-octant
// masks in SALU from 4 ballots and skip zero octants.

#define NPTS   2048
#define KSAMP  32
#define RAD2   0.16f

__device__ __forceinline__ unsigned rank_below(unsigned long long mask) {
    // number of set bits in `mask` at lane positions strictly below mine
    return __builtin_amdgcn_mbcnt_hi((unsigned)(mask >> 32),
           __builtin_amdgcn_mbcnt_lo((unsigned)(mask & 0xffffffffu), 0u));
}

__global__ __launch_bounds__(256) void octant_query_kernel(
    const float* __restrict__ pcs, int* __restrict__ out, int nwaves) {
#pragma clang fp contract(off)
    const int wave = (int)((blockIdx.x * blockDim.x + threadIdx.x) >> 6);
    const int lane = (int)(threadIdx.x & 63);
    if (wave >= nwaves) return;
    const int b = wave >> 11;        // N = 2048
    const int i = wave & (NPTS - 1);

    const float* __restrict__ px = pcs + (size_t)b * 3 * NPTS;
    const float* __restrict__ py = px + NPTS;
    const float* __restrict__ pz = py + NPTS;

    const float cx = px[i];
    const float cy = py[i];
    const float cz = pz[i];

    int* __restrict__ obase = out + (size_t)(b * NPTS + i) * 9 * KSAMP;

    int cnt0 = 0, cnt1 = 0, cnt2 = 0, cnt3 = 0;
    int cnt4 = 0, cnt5 = 0, cnt6 = 0, cnt7 = 0;

    for (int c = 0; c < NPTS; c += 64) {
        const int j = c + lane;
        const float dx = px[j] - cx;
        const float dy = py[j] - cy;
        const float dz = pz[j] - cz;
        // match numpy rounding: no fp contraction (pragma above), left-assoc
        float d2 = dx * dx;
        d2 = d2 + dy * dy;
        d2 = d2 + dz * dz;
        const bool within = (d2 < RAD2) && (j != i);
        const unsigned long long mw = __ballot(within);
        if (mw == 0ULL) continue;                 // wave-uniform skip (~70%)

        const unsigned long long mx = __ballot(dx > 0.f);
        const unsigned long long my = __ballot(dy > 0.f);
        const unsigned long long mz = __ballot(dz > 0.f);

#define DO_OCT(o, cnt)                                                      \
        {                                                                   \
            unsigned long long m = mw;                                      \
            m &= ((o) & 1) ? mx : ~mx;                                      \
            m &= ((o) & 2) ? my : ~my;                                      \
            m &= ((o) & 4) ? mz : ~mz;                                      \
            if (m) {                              /* uniform skip */        \
                const bool mine = (m >> lane) & 1ULL;                       \
                if (mine) {                                                 \
                    const int r = cnt + (int)rank_below(m);                 \
                    if (r < KSAMP) obase[(o) * KSAMP + r] = j;              \
                }                                                           \
                cnt += (int)__popcll(m);                                    \
            }                                                               \
        }
        DO_OCT(0, cnt0) DO_OCT(1, cnt1) DO_OCT(2, cnt2) DO_OCT(3, cnt3)
        DO_OCT(4, cnt4) DO_OCT(5, cnt5) DO_OCT(6, cnt6) DO_OCT(7, cnt7)
#undef DO_OCT
    }

    // pad remaining slots with center index i (each slot written exactly once)
#define FILL(o, cnt)                                                        \
        {                                                                   \
            const int s = cnt + lane;                                       \
            if (s < KSAMP) obase[(o) * KSAMP + s] = i;                      \
        }
    FILL(0, cnt0) FILL(1, cnt1) FILL(2, cnt2) FILL(3, cnt3)
    FILL(4, cnt4) FILL(5, cnt5) FILL(6, cnt6) FILL(7, cnt7)
#undef FILL
    if (lane < KSAMP) obase[8 * KSAMP + lane] = i;
}

extern "C" void kernel_launch(void* const* d_in, const int* in_sizes, int n_in,
                              void* d_out, int out_size, void* d_ws, size_t ws_size,
                              hipStream_t stream) {
    const float* pcs = (const float*)d_in[0];
    int* out = (int*)d_out;
    const int B = in_sizes[0] / (3 * NPTS);   // 4
    const int nwaves = B * NPTS;              // one wave per center
    const int block = 256;                    // 4 waves/block
    const int grid = (nwaves * 64 + block - 1) / block;
    octant_query_kernel<<<grid, block, 0, stream>>>(pcs, out, nwaves);
}